// Round 3
// baseline (398.731 us; speedup 1.0000x reference)
//
#include <hip/hip_runtime.h>

#define NNODES 100000
#define NEDGES 1600000
#define DIM    128
#define NEG_SLOPE 0.01f
#define TILE_R 32   // rows per gemm tile (100000 % 32 == 0 -> 3125 tiles)
#define NB_SCAN ((NNODES + 1023) / 1024)   // 98 blocks of 1024 counts

static inline size_t align256(size_t x) { return (x + 255) & ~(size_t)255; }

// ---------------- zero (counts / fallback hn) ----------------
__global__ __launch_bounds__(256) void zero_f32(float* __restrict__ p, int n4) {
    int i = blockIdx.x * blockDim.x + threadIdx.x;
    int stride = gridDim.x * blockDim.x;
    float4 z = make_float4(0.f, 0.f, 0.f, 0.f);
    for (; i < n4; i += stride) ((float4*)p)[i] = z;
}

// ---------------- histogram of edge destinations (4 edges/thread) ----------------
__global__ __launch_bounds__(256) void hist_dst4(const int* __restrict__ edst,
                                                 int* __restrict__ counts) {
    int i = blockIdx.x * 256 + threadIdx.x;
    if (i < NEDGES / 4) {
        int4 d = ((const int4*)edst)[i];
        atomicAdd(&counts[d.x], 1);
        atomicAdd(&counts[d.y], 1);
        atomicAdd(&counts[d.z], 1);
        atomicAdd(&counts[d.w], 1);
    }
}

// ---------------- scan step 1: per-1024-chunk exclusive scan ----------------
__global__ __launch_bounds__(256) void scan1(const int* __restrict__ counts,
                                             int* __restrict__ offsets,
                                             int* __restrict__ blocksum) {
    __shared__ int lds[256];
    int tid = threadIdx.x;
    int base = blockIdx.x * 1024 + tid * 4;
    int c0 = (base + 0 < NNODES) ? counts[base + 0] : 0;
    int c1 = (base + 1 < NNODES) ? counts[base + 1] : 0;
    int c2 = (base + 2 < NNODES) ? counts[base + 2] : 0;
    int c3 = (base + 3 < NNODES) ? counts[base + 3] : 0;
    int t = c0 + c1 + c2 + c3;
    lds[tid] = t;
    __syncthreads();
    for (int d = 1; d < 256; d <<= 1) {
        int v = lds[tid];
        int add = (tid >= d) ? lds[tid - d] : 0;
        __syncthreads();
        lds[tid] = v + add;
        __syncthreads();
    }
    int incl = lds[tid];
    int excl = incl - t;
    if (base + 0 < NNODES) offsets[base + 0] = excl;
    if (base + 1 < NNODES) offsets[base + 1] = excl + c0;
    if (base + 2 < NNODES) offsets[base + 2] = excl + c0 + c1;
    if (base + 3 < NNODES) offsets[base + 3] = excl + c0 + c1 + c2;
    if (tid == 255) blocksum[blockIdx.x] = incl;
}

// ---------------- scan step 2: serial exclusive scan of block sums ----------------
__global__ void scan2(int* __restrict__ blocksum, int nb) {
    if (blockIdx.x == 0 && threadIdx.x == 0) {
        int acc = 0;
        for (int i = 0; i < nb; ++i) { int t = blocksum[i]; blocksum[i] = acc; acc += t; }
    }
}

// ---------------- scan step 3: add block offsets, init cursor ----------------
__global__ __launch_bounds__(256) void scan3(int* __restrict__ offsets,
                                             const int* __restrict__ blocksum,
                                             int* __restrict__ cursor) {
    int add = blocksum[blockIdx.x];
    int base = blockIdx.x * 1024 + threadIdx.x * 4;
    #pragma unroll
    for (int i = 0; i < 4; ++i) {
        int idx = base + i;
        if (idx < NNODES) { int o = offsets[idx] + add; offsets[idx] = o; cursor[idx] = o; }
    }
}

// ---------------- bin fill: bucket packed (src, w) by dst, 4 edges/thread ----------------
__global__ __launch_bounds__(256) void fill_bins4(const int* __restrict__ esrc,
                                                  const int* __restrict__ edst,
                                                  const float* __restrict__ ew,
                                                  int* __restrict__ cursor,
                                                  int2* __restrict__ bins) {
    int i = blockIdx.x * 256 + threadIdx.x;
    if (i >= NEDGES / 4) return;
    int4   s = ((const int4*)esrc)[i];
    int4   d = ((const int4*)edst)[i];
    float4 w = ((const float4*)ew)[i];
    int p0 = atomicAdd(&cursor[d.x], 1);
    bins[p0] = make_int2(s.x, __float_as_int(w.x));
    int p1 = atomicAdd(&cursor[d.y], 1);
    bins[p1] = make_int2(s.y, __float_as_int(w.y));
    int p2 = atomicAdd(&cursor[d.z], 1);
    bins[p2] = make_int2(s.z, __float_as_int(w.z));
    int p3 = atomicAdd(&cursor[d.w], 1);
    bins[p3] = make_int2(s.w, __float_as_int(w.w));
}

// ---------------- pull + elementwise: x[v] = nfeat[v] .* sum_e w_e*nfeat[src_e] ----------------
// 32 lanes per node, float4 per lane; register accumulation, no atomics
__global__ __launch_bounds__(256) void pull_x(const float* __restrict__ nfeat,
                                              const int* __restrict__ offsets,
                                              const int* __restrict__ counts,
                                              const int2* __restrict__ bins,
                                              float* __restrict__ x) {
    int gid = blockIdx.x * 256 + threadIdx.x;
    int v = gid >> 5;
    int lane = gid & 31;
    if (v >= NNODES) return;
    int start = offsets[v];
    int end = start + counts[v];
    const float4* nf4 = (const float4*)nfeat;
    float4 a0 = make_float4(0.f, 0.f, 0.f, 0.f);
    float4 a1 = make_float4(0.f, 0.f, 0.f, 0.f);
    float4 a2 = make_float4(0.f, 0.f, 0.f, 0.f);
    float4 a3 = make_float4(0.f, 0.f, 0.f, 0.f);
    int k = start;
    for (; k + 4 <= end; k += 4) {
        int2 e0 = bins[k], e1 = bins[k + 1], e2 = bins[k + 2], e3 = bins[k + 3];
        float4 v0 = nf4[(size_t)e0.x * 32 + lane];
        float4 v1 = nf4[(size_t)e1.x * 32 + lane];
        float4 v2 = nf4[(size_t)e2.x * 32 + lane];
        float4 v3 = nf4[(size_t)e3.x * 32 + lane];
        float w0 = __int_as_float(e0.y), w1 = __int_as_float(e1.y);
        float w2 = __int_as_float(e2.y), w3 = __int_as_float(e3.y);
        a0.x += w0 * v0.x; a0.y += w0 * v0.y; a0.z += w0 * v0.z; a0.w += w0 * v0.w;
        a1.x += w1 * v1.x; a1.y += w1 * v1.y; a1.z += w1 * v1.z; a1.w += w1 * v1.w;
        a2.x += w2 * v2.x; a2.y += w2 * v2.y; a2.z += w2 * v2.z; a2.w += w2 * v2.w;
        a3.x += w3 * v3.x; a3.y += w3 * v3.y; a3.z += w3 * v3.z; a3.w += w3 * v3.w;
    }
    for (; k < end; ++k) {
        int2 e = bins[k];
        float w = __int_as_float(e.y);
        float4 v0 = nf4[(size_t)e.x * 32 + lane];
        a0.x += w * v0.x; a0.y += w * v0.y; a0.z += w * v0.z; a0.w += w * v0.w;
    }
    float4 acc;
    acc.x = (a0.x + a1.x) + (a2.x + a3.x);
    acc.y = (a0.y + a1.y) + (a2.y + a3.y);
    acc.z = (a0.z + a1.z) + (a2.z + a3.z);
    acc.w = (a0.w + a1.w) + (a2.w + a3.w);
    float4 nfv = nf4[(size_t)v * 32 + lane];
    acc.x *= nfv.x; acc.y *= nfv.y; acc.z *= nfv.z; acc.w *= nfv.w;
    ((float4*)x)[(size_t)v * 32 + lane] = acc;
}

// ---------------- fallback scatter (atomics) ----------------
__global__ __launch_bounds__(256) void scatter_edges(
    const float* __restrict__ nfeat, const int* __restrict__ esrc,
    const int* __restrict__ edst, const float* __restrict__ ew,
    float* __restrict__ hn) {
    long long t = (long long)blockIdx.x * 256 + threadIdx.x;
    int e = (int)(t >> 5);
    if (e >= NEDGES) return;
    int lane = (int)(t & 31);
    int s = esrc[e];
    int d = edst[e];
    float w = ew[e];
    float4 v = ((const float4*)(nfeat + (size_t)s * DIM))[lane];
    float* o = hn + (size_t)d * DIM + lane * 4;
    unsafeAtomicAdd(o + 0, v.x * w);
    unsafeAtomicAdd(o + 1, v.y * w);
    unsafeAtomicAdd(o + 2, v.z * w);
    unsafeAtomicAdd(o + 3, v.w * w);
}

// ---------------- fallback elementwise: x = nfeat .* hn (in place over hn) ----------------
__global__ __launch_bounds__(256) void elem_mul(const float* __restrict__ nfeat,
                                                float* __restrict__ hn, int n4) {
    int i = blockIdx.x * blockDim.x + threadIdx.x;
    int stride = gridDim.x * blockDim.x;
    for (; i < n4; i += stride) {
        float4 a = ((const float4*)nfeat)[i];
        float4 b = ((float4*)hn)[i];
        b.x *= a.x; b.y *= a.y; b.z *= a.z; b.w *= a.w;
        ((float4*)hn)[i] = b;
    }
}

// ---------------- out = leaky_relu(x @ W^T) ----------------
__global__ __launch_bounds__(256) void bi_gemm2(
    const float* __restrict__ x, const float* __restrict__ W,
    float* __restrict__ out) {
    extern __shared__ float lds[];
    float4* W4  = (float4*)lds;             // 128*32 float4 = 64KB
    float*  xs  = lds + 128 * 128;          // TILE_R*128 floats = 16KB
    float4* xs4 = (float4*)xs;

    int tid = threadIdx.x;

    const float4* Wg = (const float4*)W;
    for (int i = tid; i < 128 * 32; i += 256) {
        int j = i >> 5, d4 = i & 31;
        W4[(j << 5) | (d4 ^ ((j >> 2) & 7))] = Wg[i];
    }
    __syncthreads();

    int tx = tid & 31;
    int ty = tid >> 5;
    int j0 = tx << 2;
    int r0 = ty << 2;

    int ntiles = NNODES / TILE_R;
    for (int tile = blockIdx.x; tile < ntiles; tile += gridDim.x) {
        int rbase = tile * TILE_R;

        // stage x tile (fully coalesced, contiguous)
        for (int i = tid; i < TILE_R * 32; i += 256)
            xs4[i] = ((const float4*)x)[(size_t)rbase * 32 + i];
        __syncthreads();

        float acc[4][4];
        #pragma unroll
        for (int r = 0; r < 4; ++r)
            #pragma unroll
            for (int j = 0; j < 4; ++j) acc[r][j] = 0.f;

        #pragma unroll 4
        for (int d4 = 0; d4 < 32; ++d4) {
            float4 xv[4], wv[4];
            #pragma unroll
            for (int r = 0; r < 4; ++r)
                xv[r] = xs4[((r0 + r) << 5) | d4];
            #pragma unroll
            for (int j = 0; j < 4; ++j) {
                int jj = j0 + j;
                wv[j] = W4[(jj << 5) | (d4 ^ ((jj >> 2) & 7))];
            }
            #pragma unroll
            for (int r = 0; r < 4; ++r)
                #pragma unroll
                for (int j = 0; j < 4; ++j) {
                    acc[r][j] += xv[r].x * wv[j].x;
                    acc[r][j] += xv[r].y * wv[j].y;
                    acc[r][j] += xv[r].z * wv[j].z;
                    acc[r][j] += xv[r].w * wv[j].w;
                }
        }
        __syncthreads();

        #pragma unroll
        for (int r = 0; r < 4; ++r) {
            float4 o;
            o.x = acc[r][0] >= 0.f ? acc[r][0] : NEG_SLOPE * acc[r][0];
            o.y = acc[r][1] >= 0.f ? acc[r][1] : NEG_SLOPE * acc[r][1];
            o.z = acc[r][2] >= 0.f ? acc[r][2] : NEG_SLOPE * acc[r][2];
            o.w = acc[r][3] >= 0.f ? acc[r][3] : NEG_SLOPE * acc[r][3];
            size_t row = (size_t)(rbase + r0 + r);
            ((float4*)out)[row * (DIM / 4) + tx] = o;
        }
    }
}

extern "C" void kernel_launch(void* const* d_in, const int* in_sizes, int n_in,
                              void* d_out, int out_size, void* d_ws, size_t ws_size,
                              hipStream_t stream) {
    const float* nfeat = (const float*)d_in[0];
    const int*   esrc  = (const int*)d_in[1];
    const int*   edst  = (const int*)d_in[2];
    const float* ew    = (const float*)d_in[3];
    const float* W     = (const float*)d_in[4];
    float* out = (float*)d_out;

    hipFuncSetAttribute((const void*)bi_gemm2,
                        hipFuncAttributeMaxDynamicSharedMemorySize, 81920);

    // ---- workspace layout ----
    size_t off = 0;
    size_t x_off = off;        off += align256((size_t)NNODES * DIM * 4);  // 51.2 MB
    size_t cnt_off = off;      off += align256((size_t)NNODES * 4);
    size_t ofs_off = off;      off += align256((size_t)NNODES * 4);
    size_t cur_off = off;      off += align256((size_t)NNODES * 4);
    size_t bsum_off = off;     off += align256((size_t)NB_SCAN * 4);
    size_t bins_off = off;     off += align256((size_t)NEDGES * 8);        // 12.8 MB
    size_t need = off;

    char* ws = (char*)d_ws;
    float* x = (float*)(ws + x_off);

    if (ws_size >= need) {
        int* counts = (int*)(ws + cnt_off);
        int* offsets = (int*)(ws + ofs_off);
        int* cursor = (int*)(ws + cur_off);
        int* blocksum = (int*)(ws + bsum_off);
        int2* bins = (int2*)(ws + bins_off);

        zero_f32<<<128, 256, 0, stream>>>((float*)counts, NNODES / 4);
        int e4grid = (NEDGES / 4 + 255) / 256;
        hist_dst4<<<e4grid, 256, 0, stream>>>(edst, counts);
        scan1<<<NB_SCAN, 256, 0, stream>>>(counts, offsets, blocksum);
        scan2<<<1, 64, 0, stream>>>(blocksum, NB_SCAN);
        scan3<<<NB_SCAN, 256, 0, stream>>>(offsets, blocksum, cursor);
        fill_bins4<<<e4grid, 256, 0, stream>>>(esrc, edst, ew, cursor, bins);
        int pgrid = (NNODES * 32 + 255) / 256;
        pull_x<<<pgrid, 256, 0, stream>>>(nfeat, offsets, counts, bins, x);
    } else {
        // fallback: atomic scatter + elementwise
        zero_f32<<<2048, 256, 0, stream>>>(x, NNODES * DIM / 4);
        int sgrid = (NEDGES * 32 + 255) / 256;
        scatter_edges<<<sgrid, 256, 0, stream>>>(nfeat, esrc, edst, ew, x);
        elem_mul<<<2048, 256, 0, stream>>>(nfeat, x, NNODES * DIM / 4);
    }

    bi_gemm2<<<512, 256, 81920, stream>>>(x, W, out);
}

// Round 4
// 346.355 us; speedup vs baseline: 1.1512x; 1.1512x over previous
//
#include <hip/hip_runtime.h>

#define NNODES 100000
#define NEDGES 1600000
#define DIM    128
#define NEG_SLOPE 0.01f
#define TILE_R 32
#define NB_SCAN ((NNODES + 1023) / 1024)   // 98 blocks of 1024 counts
#define NPART 8
#define PART_SZ ((NNODES + NPART - 1) / NPART)   // 12500

static inline size_t align256(size_t x) { return (x + 255) & ~(size_t)255; }

// ---------------- zero (counts / fallback hn) ----------------
__global__ __launch_bounds__(256) void zero_f32(float* __restrict__ p, int n4) {
    int i = blockIdx.x * blockDim.x + threadIdx.x;
    int stride = gridDim.x * blockDim.x;
    float4 z = make_float4(0.f, 0.f, 0.f, 0.f);
    for (; i < n4; i += stride) ((float4*)p)[i] = z;
}

// ---------------- histogram of edge destinations (4 edges/thread) ----------------
__global__ __launch_bounds__(256) void hist_dst4(const int* __restrict__ edst,
                                                 int* __restrict__ counts) {
    int i = blockIdx.x * 256 + threadIdx.x;
    if (i < NEDGES / 4) {
        int4 d = ((const int4*)edst)[i];
        atomicAdd(&counts[d.x], 1);
        atomicAdd(&counts[d.y], 1);
        atomicAdd(&counts[d.z], 1);
        atomicAdd(&counts[d.w], 1);
    }
}

// ---------------- scan step 1: per-1024-chunk exclusive scan ----------------
__global__ __launch_bounds__(256) void scan1(const int* __restrict__ counts,
                                             int* __restrict__ offsets,
                                             int* __restrict__ blocksum) {
    __shared__ int lds[256];
    int tid = threadIdx.x;
    int base = blockIdx.x * 1024 + tid * 4;
    int c0 = (base + 0 < NNODES) ? counts[base + 0] : 0;
    int c1 = (base + 1 < NNODES) ? counts[base + 1] : 0;
    int c2 = (base + 2 < NNODES) ? counts[base + 2] : 0;
    int c3 = (base + 3 < NNODES) ? counts[base + 3] : 0;
    int t = c0 + c1 + c2 + c3;
    lds[tid] = t;
    __syncthreads();
    for (int d = 1; d < 256; d <<= 1) {
        int v = lds[tid];
        int add = (tid >= d) ? lds[tid - d] : 0;
        __syncthreads();
        lds[tid] = v + add;
        __syncthreads();
    }
    int incl = lds[tid];
    int excl = incl - t;
    if (base + 0 < NNODES) offsets[base + 0] = excl;
    if (base + 1 < NNODES) offsets[base + 1] = excl + c0;
    if (base + 2 < NNODES) offsets[base + 2] = excl + c0 + c1;
    if (base + 3 < NNODES) offsets[base + 3] = excl + c0 + c1 + c2;
    if (tid == 255) blocksum[blockIdx.x] = incl;
}

// ---------------- scan step 2: parallel exclusive scan of <=128 block sums ----------------
__global__ __launch_bounds__(128) void scan2p(int* __restrict__ blocksum, int nb) {
    __shared__ int lds[128];
    int tid = threadIdx.x;
    int v = (tid < nb) ? blocksum[tid] : 0;
    lds[tid] = v;
    __syncthreads();
    for (int d = 1; d < 128; d <<= 1) {
        int x = lds[tid];
        int add = (tid >= d) ? lds[tid - d] : 0;
        __syncthreads();
        lds[tid] = x + add;
        __syncthreads();
    }
    if (tid < nb) blocksum[tid] = lds[tid] - v;   // exclusive
}

// ---------------- scan step 3: add block offsets, init cursor ----------------
__global__ __launch_bounds__(256) void scan3(int* __restrict__ offsets,
                                             const int* __restrict__ blocksum,
                                             int* __restrict__ cursor) {
    int add = blocksum[blockIdx.x];
    int base = blockIdx.x * 1024 + threadIdx.x * 4;
    #pragma unroll
    for (int i = 0; i < 4; ++i) {
        int idx = base + i;
        if (idx < NNODES) { int o = offsets[idx] + add; offsets[idx] = o; cursor[idx] = o; }
    }
}

// ---------------- XCD-partitioned bin fill ----------------
// part = blockIdx % 8 -> (heuristically) one XCD per dst-range; each part's
// blocks scan all edges, keep those with dst in-range. Bins window per part
// (1.6 MB) is then written by a single XCD -> lines coalesce in its L2.
__global__ __launch_bounds__(256) void fill_part(const int* __restrict__ esrc,
                                                 const int* __restrict__ edst,
                                                 const float* __restrict__ ew,
                                                 int* __restrict__ cursor,
                                                 int2* __restrict__ bins) {
    int part = blockIdx.x & (NPART - 1);
    int lo = part * PART_SZ;
    int hi = lo + PART_SZ;
    int t = (blockIdx.x >> 3) * 256 + threadIdx.x;
    int stride = (gridDim.x >> 3) * 256;
    int nq = NEDGES / 4;
    for (int i = t; i < nq; i += stride) {
        int4 d = ((const int4*)edst)[i];
        int e = i * 4;
        if (d.x >= lo && d.x < hi) {
            int p = atomicAdd(&cursor[d.x], 1);
            bins[p] = make_int2(esrc[e + 0], __float_as_int(ew[e + 0]));
        }
        if (d.y >= lo && d.y < hi) {
            int p = atomicAdd(&cursor[d.y], 1);
            bins[p] = make_int2(esrc[e + 1], __float_as_int(ew[e + 1]));
        }
        if (d.z >= lo && d.z < hi) {
            int p = atomicAdd(&cursor[d.z], 1);
            bins[p] = make_int2(esrc[e + 2], __float_as_int(ew[e + 2]));
        }
        if (d.w >= lo && d.w < hi) {
            int p = atomicAdd(&cursor[d.w], 1);
            bins[p] = make_int2(esrc[e + 3], __float_as_int(ew[e + 3]));
        }
    }
}

// ---------------- pull + elementwise: x[v] = nfeat[v] .* sum_e w_e*nfeat[src_e] ----------------
__global__ __launch_bounds__(256) void pull_x(const float* __restrict__ nfeat,
                                              const int* __restrict__ offsets,
                                              const int* __restrict__ counts,
                                              const int2* __restrict__ bins,
                                              float* __restrict__ x) {
    int gid = blockIdx.x * 256 + threadIdx.x;
    int v = gid >> 5;
    int lane = gid & 31;
    if (v >= NNODES) return;
    int start = offsets[v];
    int end = start + counts[v];
    const float4* nf4 = (const float4*)nfeat;
    float4 a0 = make_float4(0.f, 0.f, 0.f, 0.f);
    float4 a1 = make_float4(0.f, 0.f, 0.f, 0.f);
    float4 a2 = make_float4(0.f, 0.f, 0.f, 0.f);
    float4 a3 = make_float4(0.f, 0.f, 0.f, 0.f);
    int k = start;
    for (; k + 4 <= end; k += 4) {
        int2 e0 = bins[k], e1 = bins[k + 1], e2 = bins[k + 2], e3 = bins[k + 3];
        float4 v0 = nf4[(size_t)e0.x * 32 + lane];
        float4 v1 = nf4[(size_t)e1.x * 32 + lane];
        float4 v2 = nf4[(size_t)e2.x * 32 + lane];
        float4 v3 = nf4[(size_t)e3.x * 32 + lane];
        float w0 = __int_as_float(e0.y), w1 = __int_as_float(e1.y);
        float w2 = __int_as_float(e2.y), w3 = __int_as_float(e3.y);
        a0.x += w0 * v0.x; a0.y += w0 * v0.y; a0.z += w0 * v0.z; a0.w += w0 * v0.w;
        a1.x += w1 * v1.x; a1.y += w1 * v1.y; a1.z += w1 * v1.z; a1.w += w1 * v1.w;
        a2.x += w2 * v2.x; a2.y += w2 * v2.y; a2.z += w2 * v2.z; a2.w += w2 * v2.w;
        a3.x += w3 * v3.x; a3.y += w3 * v3.y; a3.z += w3 * v3.z; a3.w += w3 * v3.w;
    }
    for (; k < end; ++k) {
        int2 e = bins[k];
        float w = __int_as_float(e.y);
        float4 v0 = nf4[(size_t)e.x * 32 + lane];
        a0.x += w * v0.x; a0.y += w * v0.y; a0.z += w * v0.z; a0.w += w * v0.w;
    }
    float4 acc;
    acc.x = (a0.x + a1.x) + (a2.x + a3.x);
    acc.y = (a0.y + a1.y) + (a2.y + a3.y);
    acc.z = (a0.z + a1.z) + (a2.z + a3.z);
    acc.w = (a0.w + a1.w) + (a2.w + a3.w);
    float4 nfv = nf4[(size_t)v * 32 + lane];
    acc.x *= nfv.x; acc.y *= nfv.y; acc.z *= nfv.z; acc.w *= nfv.w;
    ((float4*)x)[(size_t)v * 32 + lane] = acc;
}

// ---------------- fallback scatter (atomics) ----------------
__global__ __launch_bounds__(256) void scatter_edges(
    const float* __restrict__ nfeat, const int* __restrict__ esrc,
    const int* __restrict__ edst, const float* __restrict__ ew,
    float* __restrict__ hn) {
    long long t = (long long)blockIdx.x * 256 + threadIdx.x;
    int e = (int)(t >> 5);
    if (e >= NEDGES) return;
    int lane = (int)(t & 31);
    int s = esrc[e];
    int d = edst[e];
    float w = ew[e];
    float4 v = ((const float4*)(nfeat + (size_t)s * DIM))[lane];
    float* o = hn + (size_t)d * DIM + lane * 4;
    unsafeAtomicAdd(o + 0, v.x * w);
    unsafeAtomicAdd(o + 1, v.y * w);
    unsafeAtomicAdd(o + 2, v.z * w);
    unsafeAtomicAdd(o + 3, v.w * w);
}

// ---------------- fallback elementwise: x = nfeat .* hn ----------------
__global__ __launch_bounds__(256) void elem_mul(const float* __restrict__ nfeat,
                                                float* __restrict__ hn, int n4) {
    int i = blockIdx.x * blockDim.x + threadIdx.x;
    int stride = gridDim.x * blockDim.x;
    for (; i < n4; i += stride) {
        float4 a = ((const float4*)nfeat)[i];
        float4 b = ((float4*)hn)[i];
        b.x *= a.x; b.y *= a.y; b.z *= a.z; b.w *= a.w;
        ((float4*)hn)[i] = b;
    }
}

// ---------------- out = leaky_relu(x @ W^T) ----------------
__global__ __launch_bounds__(256) void bi_gemm2(
    const float* __restrict__ x, const float* __restrict__ W,
    float* __restrict__ out) {
    extern __shared__ float lds[];
    float4* W4  = (float4*)lds;             // 128*32 float4 = 64KB
    float*  xs  = lds + 128 * 128;          // TILE_R*128 floats = 16KB
    float4* xs4 = (float4*)xs;

    int tid = threadIdx.x;

    const float4* Wg = (const float4*)W;
    for (int i = tid; i < 128 * 32; i += 256) {
        int j = i >> 5, d4 = i & 31;
        W4[(j << 5) | (d4 ^ ((j >> 2) & 7))] = Wg[i];
    }
    __syncthreads();

    int tx = tid & 31;
    int ty = tid >> 5;
    int j0 = tx << 2;
    int r0 = ty << 2;

    int ntiles = NNODES / TILE_R;
    for (int tile = blockIdx.x; tile < ntiles; tile += gridDim.x) {
        int rbase = tile * TILE_R;

        for (int i = tid; i < TILE_R * 32; i += 256)
            xs4[i] = ((const float4*)x)[(size_t)rbase * 32 + i];
        __syncthreads();

        float acc[4][4];
        #pragma unroll
        for (int r = 0; r < 4; ++r)
            #pragma unroll
            for (int j = 0; j < 4; ++j) acc[r][j] = 0.f;

        #pragma unroll 4
        for (int d4 = 0; d4 < 32; ++d4) {
            float4 xv[4], wv[4];
            #pragma unroll
            for (int r = 0; r < 4; ++r)
                xv[r] = xs4[((r0 + r) << 5) | d4];
            #pragma unroll
            for (int j = 0; j < 4; ++j) {
                int jj = j0 + j;
                wv[j] = W4[(jj << 5) | (d4 ^ ((jj >> 2) & 7))];
            }
            #pragma unroll
            for (int r = 0; r < 4; ++r)
                #pragma unroll
                for (int j = 0; j < 4; ++j) {
                    acc[r][j] += xv[r].x * wv[j].x;
                    acc[r][j] += xv[r].y * wv[j].y;
                    acc[r][j] += xv[r].z * wv[j].z;
                    acc[r][j] += xv[r].w * wv[j].w;
                }
        }
        __syncthreads();

        #pragma unroll
        for (int r = 0; r < 4; ++r) {
            float4 o;
            o.x = acc[r][0] >= 0.f ? acc[r][0] : NEG_SLOPE * acc[r][0];
            o.y = acc[r][1] >= 0.f ? acc[r][1] : NEG_SLOPE * acc[r][1];
            o.z = acc[r][2] >= 0.f ? acc[r][2] : NEG_SLOPE * acc[r][2];
            o.w = acc[r][3] >= 0.f ? acc[r][3] : NEG_SLOPE * acc[r][3];
            size_t row = (size_t)(rbase + r0 + r);
            ((float4*)out)[row * (DIM / 4) + tx] = o;
        }
    }
}

extern "C" void kernel_launch(void* const* d_in, const int* in_sizes, int n_in,
                              void* d_out, int out_size, void* d_ws, size_t ws_size,
                              hipStream_t stream) {
    const float* nfeat = (const float*)d_in[0];
    const int*   esrc  = (const int*)d_in[1];
    const int*   edst  = (const int*)d_in[2];
    const float* ew    = (const float*)d_in[3];
    const float* W     = (const float*)d_in[4];
    float* out = (float*)d_out;

    hipFuncSetAttribute((const void*)bi_gemm2,
                        hipFuncAttributeMaxDynamicSharedMemorySize, 81920);

    // ---- workspace layout ----
    size_t off = 0;
    size_t x_off = off;        off += align256((size_t)NNODES * DIM * 4);  // 51.2 MB
    size_t cnt_off = off;      off += align256((size_t)NNODES * 4);
    size_t ofs_off = off;      off += align256((size_t)NNODES * 4);
    size_t cur_off = off;      off += align256((size_t)NNODES * 4);
    size_t bsum_off = off;     off += align256((size_t)NB_SCAN * 4);
    size_t bins_off = off;     off += align256((size_t)NEDGES * 8);        // 12.8 MB
    size_t need = off;

    char* ws = (char*)d_ws;
    float* x = (float*)(ws + x_off);

    if (ws_size >= need) {
        int* counts = (int*)(ws + cnt_off);
        int* offsets = (int*)(ws + ofs_off);
        int* cursor = (int*)(ws + cur_off);
        int* blocksum = (int*)(ws + bsum_off);
        int2* bins = (int2*)(ws + bins_off);

        zero_f32<<<128, 256, 0, stream>>>((float*)counts, NNODES / 4);
        int e4grid = (NEDGES / 4 + 255) / 256;
        hist_dst4<<<e4grid, 256, 0, stream>>>(edst, counts);
        scan1<<<NB_SCAN, 256, 0, stream>>>(counts, offsets, blocksum);
        scan2p<<<1, 128, 0, stream>>>(blocksum, NB_SCAN);
        scan3<<<NB_SCAN, 256, 0, stream>>>(offsets, blocksum, cursor);
        fill_part<<<2048, 256, 0, stream>>>(esrc, edst, ew, cursor, bins);
        int pgrid = (NNODES * 32 + 255) / 256;
        pull_x<<<pgrid, 256, 0, stream>>>(nfeat, offsets, counts, bins, x);
    } else {
        // fallback: atomic scatter + elementwise
        zero_f32<<<2048, 256, 0, stream>>>(x, NNODES * DIM / 4);
        int sgrid = (NEDGES * 32 + 255) / 256;
        scatter_edges<<<sgrid, 256, 0, stream>>>(nfeat, esrc, edst, ew, x);
        elem_mul<<<2048, 256, 0, stream>>>(nfeat, x, NNODES * DIM / 4);
    }

    bi_gemm2<<<512, 256, 81920, stream>>>(x, W, out);
}

// Round 5
// 254.685 us; speedup vs baseline: 1.5656x; 1.3599x over previous
//
#include <hip/hip_runtime.h>
#include <hip/hip_fp16.h>

#define NNODES 100000
#define NEDGES 1600000
#define DIM    128
#define NEG_SLOPE 0.01f
#define NB_SCAN ((NNODES + 1023) / 1024)   // 98 blocks of 1024 counts
#define NPART 8
#define PART_SZ ((NNODES + NPART - 1) / NPART)   // 12500
#define GEMM_TILES ((NNODES + 63) / 64)          // 1563

typedef _Float16 v8h __attribute__((ext_vector_type(8)));
typedef float    v4f __attribute__((ext_vector_type(4)));

static inline size_t align256(size_t x) { return (x + 255) & ~(size_t)255; }

union HU { unsigned int u; __half2 h; };

// ---------------- zero ----------------
__global__ __launch_bounds__(256) void zero_f32(float* __restrict__ p, int n4) {
    int i = blockIdx.x * blockDim.x + threadIdx.x;
    int stride = gridDim.x * blockDim.x;
    float4 z = make_float4(0.f, 0.f, 0.f, 0.f);
    for (; i < n4; i += stride) ((float4*)p)[i] = z;
}

// ---------------- convert nfeat f32 -> f16 ----------------
__global__ __launch_bounds__(256) void convert_f16(const float* __restrict__ nf,
                                                   __half* __restrict__ nf16, int n4) {
    int i = blockIdx.x * blockDim.x + threadIdx.x;
    int stride = gridDim.x * blockDim.x;
    for (; i < n4; i += stride) {
        float4 v = ((const float4*)nf)[i];
        HU a, b;
        a.h = __float22half2_rn(make_float2(v.x, v.y));
        b.h = __float22half2_rn(make_float2(v.z, v.w));
        ((uint2*)nf16)[i] = make_uint2(a.u, b.u);
    }
}

// ---------------- histogram of edge destinations (4 edges/thread) ----------------
__global__ __launch_bounds__(256) void hist_dst4(const int* __restrict__ edst,
                                                 int* __restrict__ counts) {
    int i = blockIdx.x * 256 + threadIdx.x;
    if (i < NEDGES / 4) {
        int4 d = ((const int4*)edst)[i];
        atomicAdd(&counts[d.x], 1);
        atomicAdd(&counts[d.y], 1);
        atomicAdd(&counts[d.z], 1);
        atomicAdd(&counts[d.w], 1);
    }
}

// ---------------- scan step 1 ----------------
__global__ __launch_bounds__(256) void scan1(const int* __restrict__ counts,
                                             int* __restrict__ offsets,
                                             int* __restrict__ blocksum) {
    __shared__ int lds[256];
    int tid = threadIdx.x;
    int base = blockIdx.x * 1024 + tid * 4;
    int c0 = (base + 0 < NNODES) ? counts[base + 0] : 0;
    int c1 = (base + 1 < NNODES) ? counts[base + 1] : 0;
    int c2 = (base + 2 < NNODES) ? counts[base + 2] : 0;
    int c3 = (base + 3 < NNODES) ? counts[base + 3] : 0;
    int t = c0 + c1 + c2 + c3;
    lds[tid] = t;
    __syncthreads();
    for (int d = 1; d < 256; d <<= 1) {
        int v = lds[tid];
        int add = (tid >= d) ? lds[tid - d] : 0;
        __syncthreads();
        lds[tid] = v + add;
        __syncthreads();
    }
    int incl = lds[tid];
    int excl = incl - t;
    if (base + 0 < NNODES) offsets[base + 0] = excl;
    if (base + 1 < NNODES) offsets[base + 1] = excl + c0;
    if (base + 2 < NNODES) offsets[base + 2] = excl + c0 + c1;
    if (base + 3 < NNODES) offsets[base + 3] = excl + c0 + c1 + c2;
    if (tid == 255) blocksum[blockIdx.x] = incl;
}

// ---------------- scan step 2: parallel exclusive scan ----------------
__global__ __launch_bounds__(128) void scan2p(int* __restrict__ blocksum, int nb) {
    __shared__ int lds[128];
    int tid = threadIdx.x;
    int v = (tid < nb) ? blocksum[tid] : 0;
    lds[tid] = v;
    __syncthreads();
    for (int d = 1; d < 128; d <<= 1) {
        int x = lds[tid];
        int add = (tid >= d) ? lds[tid - d] : 0;
        __syncthreads();
        lds[tid] = x + add;
        __syncthreads();
    }
    if (tid < nb) blocksum[tid] = lds[tid] - v;   // exclusive
}

// ---------------- scan step 3 ----------------
__global__ __launch_bounds__(256) void scan3(int* __restrict__ offsets,
                                             const int* __restrict__ blocksum,
                                             int* __restrict__ cursor) {
    int add = blocksum[blockIdx.x];
    int base = blockIdx.x * 1024 + threadIdx.x * 4;
    #pragma unroll
    for (int i = 0; i < 4; ++i) {
        int idx = base + i;
        if (idx < NNODES) { int o = offsets[idx] + add; offsets[idx] = o; cursor[idx] = o; }
    }
}

// ---------------- XCD-partitioned bin fill ----------------
__global__ __launch_bounds__(256) void fill_part(const int* __restrict__ esrc,
                                                 const int* __restrict__ edst,
                                                 const float* __restrict__ ew,
                                                 int* __restrict__ cursor,
                                                 int2* __restrict__ bins) {
    int part = blockIdx.x & (NPART - 1);
    int lo = part * PART_SZ;
    int hi = lo + PART_SZ;
    int t = (blockIdx.x >> 3) * 256 + threadIdx.x;
    int stride = (gridDim.x >> 3) * 256;
    int nq = NEDGES / 4;
    for (int i = t; i < nq; i += stride) {
        int4 d = ((const int4*)edst)[i];
        int e = i * 4;
        if (d.x >= lo && d.x < hi) {
            int p = atomicAdd(&cursor[d.x], 1);
            bins[p] = make_int2(esrc[e + 0], __float_as_int(ew[e + 0]));
        }
        if (d.y >= lo && d.y < hi) {
            int p = atomicAdd(&cursor[d.y], 1);
            bins[p] = make_int2(esrc[e + 1], __float_as_int(ew[e + 1]));
        }
        if (d.z >= lo && d.z < hi) {
            int p = atomicAdd(&cursor[d.z], 1);
            bins[p] = make_int2(esrc[e + 2], __float_as_int(ew[e + 2]));
        }
        if (d.w >= lo && d.w < hi) {
            int p = atomicAdd(&cursor[d.w], 1);
            bins[p] = make_int2(esrc[e + 3], __float_as_int(ew[e + 3]));
        }
    }
}

// ---------------- pull (f16 gather) + elementwise, write x as f16 ----------------
__global__ __launch_bounds__(256) void pull_x16(const __half* __restrict__ nf16,
                                                const int* __restrict__ offsets,
                                                const int* __restrict__ counts,
                                                const int2* __restrict__ bins,
                                                __half* __restrict__ x16) {
    int gid = blockIdx.x * 256 + threadIdx.x;
    int v = gid >> 5;
    int lane = gid & 31;
    if (v >= NNODES) return;
    int start = offsets[v];
    int end = start + counts[v];
    const uint2* nf2 = (const uint2*)nf16;   // 4 halves per uint2; row = 32 uint2
    float4 a0 = make_float4(0.f, 0.f, 0.f, 0.f);
    float4 a1 = make_float4(0.f, 0.f, 0.f, 0.f);
    float4 a2 = make_float4(0.f, 0.f, 0.f, 0.f);
    float4 a3 = make_float4(0.f, 0.f, 0.f, 0.f);
    int k = start;
    for (; k + 4 <= end; k += 4) {
        int2 e0 = bins[k], e1 = bins[k + 1], e2 = bins[k + 2], e3 = bins[k + 3];
        uint2 u0 = nf2[(size_t)e0.x * 32 + lane];
        uint2 u1 = nf2[(size_t)e1.x * 32 + lane];
        uint2 u2 = nf2[(size_t)e2.x * 32 + lane];
        uint2 u3 = nf2[(size_t)e3.x * 32 + lane];
        float w0 = __int_as_float(e0.y), w1 = __int_as_float(e1.y);
        float w2 = __int_as_float(e2.y), w3 = __int_as_float(e3.y);
        HU h; float2 f;
        h.u = u0.x; f = __half22float2(h.h); a0.x += w0 * f.x; a0.y += w0 * f.y;
        h.u = u0.y; f = __half22float2(h.h); a0.z += w0 * f.x; a0.w += w0 * f.y;
        h.u = u1.x; f = __half22float2(h.h); a1.x += w1 * f.x; a1.y += w1 * f.y;
        h.u = u1.y; f = __half22float2(h.h); a1.z += w1 * f.x; a1.w += w1 * f.y;
        h.u = u2.x; f = __half22float2(h.h); a2.x += w2 * f.x; a2.y += w2 * f.y;
        h.u = u2.y; f = __half22float2(h.h); a2.z += w2 * f.x; a2.w += w2 * f.y;
        h.u = u3.x; f = __half22float2(h.h); a3.x += w3 * f.x; a3.y += w3 * f.y;
        h.u = u3.y; f = __half22float2(h.h); a3.z += w3 * f.x; a3.w += w3 * f.y;
    }
    for (; k < end; ++k) {
        int2 e = bins[k];
        float w = __int_as_float(e.y);
        uint2 u = nf2[(size_t)e.x * 32 + lane];
        HU h; float2 f;
        h.u = u.x; f = __half22float2(h.h); a0.x += w * f.x; a0.y += w * f.y;
        h.u = u.y; f = __half22float2(h.h); a0.z += w * f.x; a0.w += w * f.y;
    }
    float4 acc;
    acc.x = (a0.x + a1.x) + (a2.x + a3.x);
    acc.y = (a0.y + a1.y) + (a2.y + a3.y);
    acc.z = (a0.z + a1.z) + (a2.z + a3.z);
    acc.w = (a0.w + a1.w) + (a2.w + a3.w);
    // elementwise multiply by nfeat (f16 copy)
    uint2 un = nf2[(size_t)v * 32 + lane];
    HU h; float2 f;
    h.u = un.x; f = __half22float2(h.h); acc.x *= f.x; acc.y *= f.y;
    h.u = un.y; f = __half22float2(h.h); acc.z *= f.x; acc.w *= f.y;
    HU o0, o1;
    o0.h = __float22half2_rn(make_float2(acc.x, acc.y));
    o1.h = __float22half2_rn(make_float2(acc.z, acc.w));
    ((uint2*)x16)[(size_t)v * 32 + lane] = make_uint2(o0.u, o1.u);
}

// ---------------- MFMA gemm: out = leaky_relu(x16 @ W^T), W converted in-kernel ----------------
// 64 rows per block, 4 waves (16 rows each), f16 operands, f32 accumulate.
// LDS XOR-chunk swizzle: chunk (8 halves) at row r, col c stored at c^(r&7).
__global__ __launch_bounds__(256) void gemm16(const __half* __restrict__ x16,
                                              const float* __restrict__ W,
                                              float* __restrict__ out) {
    __shared__ _Float16 Wl[128 * 128];   // 32 KB
    __shared__ _Float16 Xl[64 * 128];    // 16 KB
    int tid = threadIdx.x;

    // stage W: f32 -> f16, swizzled (2048 chunks of 8 halves)
    const float4* Wg = (const float4*)W;
    for (int i = tid; i < 2048; i += 256) {
        int r = i >> 4, c = i & 15;
        float4 lo = Wg[(r * 128 + c * 8) >> 2];
        float4 hi = Wg[((r * 128 + c * 8) >> 2) + 1];
        v8h h;
        h[0] = (_Float16)lo.x; h[1] = (_Float16)lo.y; h[2] = (_Float16)lo.z; h[3] = (_Float16)lo.w;
        h[4] = (_Float16)hi.x; h[5] = (_Float16)hi.y; h[6] = (_Float16)hi.z; h[7] = (_Float16)hi.w;
        *(v8h*)&Wl[r * 128 + (c ^ (r & 7)) * 8] = h;
    }

    int rbase = blockIdx.x * 64;
    // stage X tile: 1024 chunks of 8 halves, guarded
    const uint4* xg = (const uint4*)x16;   // row = 16 uint4
    for (int i = tid; i < 1024; i += 256) {
        int r = i >> 4, c = i & 15;
        int grow = rbase + r;
        uint4 u = make_uint4(0u, 0u, 0u, 0u);
        if (grow < NNODES) u = xg[(size_t)grow * 16 + c];
        *(uint4*)&Xl[r * 128 + (c ^ (r & 7)) * 8] = u;
    }
    __syncthreads();

    int wave = tid >> 6;
    int lane = tid & 63;
    int n = lane & 15;
    int g = lane >> 4;

    v4f acc[8];
    #pragma unroll
    for (int jb = 0; jb < 8; ++jb) acc[jb] = (v4f){0.f, 0.f, 0.f, 0.f};

    #pragma unroll
    for (int kb = 0; kb < 4; ++kb) {
        // A: row = wave*16 + n (within tile), k-chunk = kb*4 + g
        v8h a = *(v8h*)&Xl[(wave * 16 + n) * 128 + (((kb * 4 + g) ^ (n & 7)) * 8)];
        #pragma unroll
        for (int jb = 0; jb < 8; ++jb) {
            // B: W row = jb*16 + n, k-chunk = kb*4 + g
            v8h b = *(v8h*)&Wl[(jb * 16 + n) * 128 + (((kb * 4 + g) ^ (n & 7)) * 8)];
            acc[jb] = __builtin_amdgcn_mfma_f32_16x16x32_f16(a, b, acc[jb], 0, 0, 0);
        }
    }

    // epilogue: C/D layout col = lane&15, row = g*4 + reg
    int row0 = rbase + wave * 16 + g * 4;
    #pragma unroll
    for (int jb = 0; jb < 8; ++jb) {
        #pragma unroll
        for (int reg = 0; reg < 4; ++reg) {
            int r = row0 + reg;
            if (r < NNODES) {
                float v = acc[jb][reg];
                v = v >= 0.f ? v : NEG_SLOPE * v;
                out[(size_t)r * 128 + jb * 16 + n] = v;
            }
        }
    }
}

// ---------------- fallback path (f32, atomic scatter) ----------------
__global__ __launch_bounds__(256) void scatter_edges(
    const float* __restrict__ nfeat, const int* __restrict__ esrc,
    const int* __restrict__ edst, const float* __restrict__ ew,
    float* __restrict__ hn) {
    long long t = (long long)blockIdx.x * 256 + threadIdx.x;
    int e = (int)(t >> 5);
    if (e >= NEDGES) return;
    int lane = (int)(t & 31);
    int s = esrc[e];
    int d = edst[e];
    float w = ew[e];
    float4 v = ((const float4*)(nfeat + (size_t)s * DIM))[lane];
    float* o = hn + (size_t)d * DIM + lane * 4;
    unsafeAtomicAdd(o + 0, v.x * w);
    unsafeAtomicAdd(o + 1, v.y * w);
    unsafeAtomicAdd(o + 2, v.z * w);
    unsafeAtomicAdd(o + 3, v.w * w);
}

__global__ __launch_bounds__(256) void elem_mul(const float* __restrict__ nfeat,
                                                float* __restrict__ hn, int n4) {
    int i = blockIdx.x * blockDim.x + threadIdx.x;
    int stride = gridDim.x * blockDim.x;
    for (; i < n4; i += stride) {
        float4 a = ((const float4*)nfeat)[i];
        float4 b = ((float4*)hn)[i];
        b.x *= a.x; b.y *= a.y; b.z *= a.z; b.w *= a.w;
        ((float4*)hn)[i] = b;
    }
}

__global__ __launch_bounds__(256) void bi_gemm2(
    const float* __restrict__ x, const float* __restrict__ W,
    float* __restrict__ out) {
    extern __shared__ float lds[];
    float4* W4  = (float4*)lds;
    float*  xs  = lds + 128 * 128;
    float4* xs4 = (float4*)xs;
    int tid = threadIdx.x;
    const float4* Wg = (const float4*)W;
    for (int i = tid; i < 128 * 32; i += 256) {
        int j = i >> 5, d4 = i & 31;
        W4[(j << 5) | (d4 ^ ((j >> 2) & 7))] = Wg[i];
    }
    __syncthreads();
    int tx = tid & 31, ty = tid >> 5;
    int j0 = tx << 2, r0 = ty << 2;
    int ntiles = NNODES / 32;
    for (int tile = blockIdx.x; tile < ntiles; tile += gridDim.x) {
        int rbase = tile * 32;
        for (int i = tid; i < 32 * 32; i += 256)
            xs4[i] = ((const float4*)x)[(size_t)rbase * 32 + i];
        __syncthreads();
        float acc[4][4];
        #pragma unroll
        for (int r = 0; r < 4; ++r)
            #pragma unroll
            for (int j = 0; j < 4; ++j) acc[r][j] = 0.f;
        #pragma unroll 4
        for (int d4 = 0; d4 < 32; ++d4) {
            float4 xv[4], wv[4];
            #pragma unroll
            for (int r = 0; r < 4; ++r) xv[r] = xs4[((r0 + r) << 5) | d4];
            #pragma unroll
            for (int j = 0; j < 4; ++j) {
                int jj = j0 + j;
                wv[j] = W4[(jj << 5) | (d4 ^ ((jj >> 2) & 7))];
            }
            #pragma unroll
            for (int r = 0; r < 4; ++r)
                #pragma unroll
                for (int j = 0; j < 4; ++j) {
                    acc[r][j] += xv[r].x * wv[j].x;
                    acc[r][j] += xv[r].y * wv[j].y;
                    acc[r][j] += xv[r].z * wv[j].z;
                    acc[r][j] += xv[r].w * wv[j].w;
                }
        }
        __syncthreads();
        #pragma unroll
        for (int r = 0; r < 4; ++r) {
            float4 o;
            o.x = acc[r][0] >= 0.f ? acc[r][0] : NEG_SLOPE * acc[r][0];
            o.y = acc[r][1] >= 0.f ? acc[r][1] : NEG_SLOPE * acc[r][1];
            o.z = acc[r][2] >= 0.f ? acc[r][2] : NEG_SLOPE * acc[r][2];
            o.w = acc[r][3] >= 0.f ? acc[r][3] : NEG_SLOPE * acc[r][3];
            size_t row = (size_t)(rbase + r0 + r);
            ((float4*)out)[row * (DIM / 4) + tx] = o;
        }
    }
}

extern "C" void kernel_launch(void* const* d_in, const int* in_sizes, int n_in,
                              void* d_out, int out_size, void* d_ws, size_t ws_size,
                              hipStream_t stream) {
    const float* nfeat = (const float*)d_in[0];
    const int*   esrc  = (const int*)d_in[1];
    const int*   edst  = (const int*)d_in[2];
    const float* ew    = (const float*)d_in[3];
    const float* W     = (const float*)d_in[4];
    float* out = (float*)d_out;

    // ---- workspace layout ----
    size_t off = 0;
    size_t nf16_off = off;     off += align256((size_t)NNODES * DIM * 2);  // 25.6 MB
    size_t x16_off = off;      off += align256((size_t)NNODES * DIM * 2);  // 25.6 MB
    size_t cnt_off = off;      off += align256((size_t)NNODES * 4);
    size_t ofs_off = off;      off += align256((size_t)NNODES * 4);
    size_t cur_off = off;      off += align256((size_t)NNODES * 4);
    size_t bsum_off = off;     off += align256((size_t)NB_SCAN * 4);
    size_t bins_off = off;     off += align256((size_t)NEDGES * 8);        // 12.8 MB
    size_t need = off;

    char* ws = (char*)d_ws;

    if (ws_size >= need) {
        __half* nf16 = (__half*)(ws + nf16_off);
        __half* x16  = (__half*)(ws + x16_off);
        int* counts = (int*)(ws + cnt_off);
        int* offsets = (int*)(ws + ofs_off);
        int* cursor = (int*)(ws + cur_off);
        int* blocksum = (int*)(ws + bsum_off);
        int2* bins = (int2*)(ws + bins_off);

        zero_f32<<<128, 256, 0, stream>>>((float*)counts, NNODES / 4);
        convert_f16<<<2048, 256, 0, stream>>>(nfeat, nf16, NNODES * DIM / 4);
        int e4grid = (NEDGES / 4 + 255) / 256;
        hist_dst4<<<e4grid, 256, 0, stream>>>(edst, counts);
        scan1<<<NB_SCAN, 256, 0, stream>>>(counts, offsets, blocksum);
        scan2p<<<1, 128, 0, stream>>>(blocksum, NB_SCAN);
        scan3<<<NB_SCAN, 256, 0, stream>>>(offsets, blocksum, cursor);
        fill_part<<<2048, 256, 0, stream>>>(esrc, edst, ew, cursor, bins);
        int pgrid = (NNODES * 32 + 255) / 256;
        pull_x16<<<pgrid, 256, 0, stream>>>(nf16, offsets, counts, bins, x16);
        gemm16<<<GEMM_TILES, 256, 0, stream>>>(x16, W, out);
    } else {
        // fallback: f32 atomic scatter + elementwise + VALU gemm
        float* hn = (float*)ws;   // reuse first 51.2 MB
        hipFuncSetAttribute((const void*)bi_gemm2,
                            hipFuncAttributeMaxDynamicSharedMemorySize, 81920);
        zero_f32<<<2048, 256, 0, stream>>>(hn, NNODES * DIM / 4);
        int sgrid = (NEDGES * 32 + 255) / 256;
        scatter_edges<<<sgrid, 256, 0, stream>>>(nfeat, esrc, edst, ew, hn);
        elem_mul<<<2048, 256, 0, stream>>>(nfeat, hn, NNODES * DIM / 4);
        bi_gemm2<<<512, 256, 81920, stream>>>(hn, W, out);
    }
}